// Round 12
// baseline (12.154 us; speedup 1.0000x reference)
//
#include <hip/hip_runtime.h>
#include <math.h>

#define NN 4096
#define BLK 512
#define EPT 8
#define PADSZ (NN + 2 * (NN >> 4))   // jj = j + 2*(j>>4): P0 runs 16B-aligned (b128), strided 4-way b64

__device__ __forceinline__ void cmul(float& ar, float& ai, float br, float bi) {
    float nr = ar * br - ai * bi;
    float ni = ar * bi + ai * br;
    ar = nr; ai = ni;
}

// new_u = u + i*w ; new_w = w + i*u  (1/sqrt2 folded into theta/phi tables)
__device__ __forceinline__ void bfly_pair(float* vr, float* vi, int a, int b) {
    float ur = vr[a], ui = vi[a], wr = vr[b], wi = vi[b];
    vr[a] = ur - wi; vi[a] = ui + wr;
    vr[b] = wr - ui; vi[b] = wi + ur;
}

__device__ __forceinline__ void bfly3(float* vr, float* vi) {
    bfly_pair(vr, vi, 0, 1); bfly_pair(vr, vi, 2, 3); bfly_pair(vr, vi, 4, 5); bfly_pair(vr, vi, 6, 7);
    bfly_pair(vr, vi, 0, 2); bfly_pair(vr, vi, 1, 3); bfly_pair(vr, vi, 4, 6); bfly_pair(vr, vi, 5, 7);
    bfly_pair(vr, vi, 0, 4); bfly_pair(vr, vi, 1, 5); bfly_pair(vr, vi, 2, 6); bfly_pair(vr, vi, 3, 7);
}

template<int P>
__device__ __forceinline__ int jidx(int t, int r) {
    return ((t >> P) << (P + 3)) | (r << P) | (t & ((1 << P) - 1));
}

__device__ __forceinline__ int pidx(int j) { return j + 2 * (j >> 4); }

// strided-side write/read (b64 per element, 4-way banks = R6 floor)
template<int P>
__device__ __forceinline__ void wr_str(float2* buf, const float* vr, const float* vi, int t) {
    #pragma unroll
    for (int r = 0; r < EPT; ++r) buf[pidx(jidx<P>(t, r))] = make_float2(vr[r], vi[r]);
}
template<int P>
__device__ __forceinline__ void rd_str(const float2* buf, float* vr, float* vi, int t) {
    #pragma unroll
    for (int r = 0; r < EPT; ++r) {
        float2 v = buf[pidx(jidx<P>(t, r))];
        vr[r] = v.x; vi[r] = v.y;
    }
}

// P=0-side write/read: contiguous 8-run, 16B-aligned -> 4x b128, banks perfectly uniform
__device__ __forceinline__ void wr_p0(float2* buf, const float* vr, const float* vi, int t) {
    float4* b4 = (float4*)buf;
    const int base = 4 * t + (t >> 1);   // pidx(8t)/2
    #pragma unroll
    for (int k = 0; k < 4; ++k)
        b4[base + k] = make_float4(vr[2*k], vi[2*k], vr[2*k+1], vi[2*k+1]);
}
__device__ __forceinline__ void rd_p0(const float2* buf, float* vr, float* vi, int t) {
    const float4* b4 = (const float4*)buf;
    const int base = 4 * t + (t >> 1);
    #pragma unroll
    for (int k = 0; k < 4; ++k) {
        float4 v = b4[base + k];
        vr[2*k] = v.x; vi[2*k] = v.y; vr[2*k+1] = v.z; vi[2*k+1] = v.w;
    }
}

__global__ __launch_bounds__(BLK) void qubit_layer_kernel(
    const float* __restrict__ x,
    const float* __restrict__ alphas, const float* __restrict__ betas,
    const float* __restrict__ thetas, const float* __restrict__ phis,
    float* __restrict__ out)
{
    __shared__ float2 B1[PADSZ];
    __shared__ float2 B2[PADSZ];
    __shared__ float2 tbl[6][64];   // 0=in_lo 1=in_hi 2=th_lo(/64) 3=th_hi 4=ph_lo(/64) 5=ph_hi

    const int t = threadIdx.x;
    const int b = blockIdx.x;

    // ---- issue global loads first (P=0 layout: j = 8t + r) ----
    const float* xr = x + (size_t)b * 2 * NN;
    const float* xi = xr + NN;
    float4 a0 = ((const float4*)(xr + t * EPT))[0];
    float4 a1 = ((const float4*)(xr + t * EPT))[1];
    float4 c0 = ((const float4*)(xi + t * EPT))[0];
    float4 c1 = ((const float4*)(xi + t * EPT))[1];

    // ---- build phase tables (1 sincos per builder thread) ----
    if (t < 384) {
        int part = t >> 6, idx = t & 63, set = part >> 1, half = part & 1;
        float a = 0.f;
        #pragma unroll
        for (int m = 0; m < 6; ++m) {
            int q = half ? m : (6 + m);
            int bit = (idx >> (5 - m)) & 1;
            float av, bv;
            if (set == 0)      { av = alphas[q]; bv = betas[q]; }
            else if (set == 1) { av = thetas[q]; bv = 0.f; }
            else               { av = phis[q];   bv = 0.f; }
            a += bit ? bv : av;
        }
        float s, c;
        __sincosf(a, &s, &c);
        float sc = (set >= 1 && half == 0) ? (1.0f / 64.0f) : 1.0f;
        tbl[part][idx] = make_float2(c * sc, s * sc);
    }

    float vr[EPT], vi[EPT];
    vr[0]=a0.x; vr[1]=a0.y; vr[2]=a0.z; vr[3]=a0.w; vr[4]=a1.x; vr[5]=a1.y; vr[6]=a1.z; vr[7]=a1.w;
    vi[0]=c0.x; vi[1]=c0.y; vi[2]=c0.z; vi[3]=c0.w; vi[4]=c1.x; vi[5]=c1.y; vi[6]=c1.z; vi[7]=c1.w;

    __syncthreads();   // tables ready

    // ---- D_in at P=0: l = (t&7)*8 + r (b128 table reads), h = t>>3 (broadcast) ----
    {
        float2 eh = tbl[1][t >> 3];
        const float4* elv = (const float4*)&tbl[0][(t & 7) << 3];
        #pragma unroll
        for (int k = 0; k < 4; ++k) {
            float4 e2 = elv[k];
            float er0 = e2.x, ei0 = e2.y, er1 = e2.z, ei1 = e2.w;
            cmul(er0, ei0, eh.x, eh.y);
            cmul(er1, ei1, eh.x, eh.y);
            cmul(vr[2*k],   vi[2*k],   er0, ei0);
            cmul(vr[2*k+1], vi[2*k+1], er1, ei1);
        }
    }

    // ---- BS1: bits 0-2 | 3-5 | 6-8 | 9-11 ----
    bfly3(vr, vi);
    // ex<0,3> wave-private: wave bits j[11:9]=t[8:6] invariant
    wr_p0(B1, vr, vi, t); asm volatile("" ::: "memory"); rd_str<3>(B1, vr, vi, t);
    bfly3(vr, vi);
    // ex<3,6> wave-private
    wr_str<3>(B1, vr, vi, t); asm volatile("" ::: "memory"); rd_str<6>(B1, vr, vi, t);
    bfly3(vr, vi);
    // ex<6,9> cross-wave
    wr_str<6>(B1, vr, vi, t); __syncthreads(); rd_str<9>(B1, vr, vi, t);
    bfly3(vr, vi);

    // ---- D_theta at P=9 (j = r*512 + t): l = t&63, h = (t>>6) + 8r ----
    {
        float2 el = tbl[2][t & 63];
        #pragma unroll
        for (int r = 0; r < EPT; ++r) {
            float2 eh = tbl[3][(t >> 6) + (r << 3)];
            float er = el.x, ei = el.y;
            cmul(er, ei, eh.x, eh.y);
            cmul(vr[r], vi[r], er, ei);
        }
    }

    // ---- BS2 down-ladder: bits 9-11 | 6-8 | 3-5 | 0-2 ----
    bfly3(vr, vi);
    // ex<9,6> cross-wave (fresh buffer B2 avoids WAR with pending rd<9> on B1)
    wr_str<9>(B2, vr, vi, t); __syncthreads(); rd_str<6>(B2, vr, vi, t);
    bfly3(vr, vi);
    // ex<6,3> wave-private (B1 safe: all rd<9>(B1) drained at the barrier above)
    wr_str<6>(B1, vr, vi, t); asm volatile("" ::: "memory"); rd_str<3>(B1, vr, vi, t);
    bfly3(vr, vi);
    // ex<3,0> wave-private, b128 read side
    wr_str<3>(B1, vr, vi, t); asm volatile("" ::: "memory"); rd_p0(B1, vr, vi, t);
    bfly3(vr, vi);

    // ---- D_phi at P=0 + float4 stores ----
    {
        float2 eh = tbl[5][t >> 3];
        const float4* elv = (const float4*)&tbl[4][(t & 7) << 3];
        #pragma unroll
        for (int k = 0; k < 4; ++k) {
            float4 e2 = elv[k];
            float er0 = e2.x, ei0 = e2.y, er1 = e2.z, ei1 = e2.w;
            cmul(er0, ei0, eh.x, eh.y);
            cmul(er1, ei1, eh.x, eh.y);
            cmul(vr[2*k],   vi[2*k],   er0, ei0);
            cmul(vr[2*k+1], vi[2*k+1], er1, ei1);
        }
    }
    float* outr = out + (size_t)b * 2 * NN;
    float* outi = outr + NN;
    ((float4*)(outr + t * EPT))[0] = make_float4(vr[0], vr[1], vr[2], vr[3]);
    ((float4*)(outr + t * EPT))[1] = make_float4(vr[4], vr[5], vr[6], vr[7]);
    ((float4*)(outi + t * EPT))[0] = make_float4(vi[0], vi[1], vi[2], vi[3]);
    ((float4*)(outi + t * EPT))[1] = make_float4(vi[4], vi[5], vi[6], vi[7]);
}

extern "C" void kernel_launch(void* const* d_in, const int* in_sizes, int n_in,
                              void* d_out, int out_size, void* d_ws, size_t ws_size,
                              hipStream_t stream) {
    const float* x      = (const float*)d_in[0];
    const float* alphas = (const float*)d_in[1];
    const float* betas  = (const float*)d_in[2];
    const float* thetas = (const float*)d_in[3];
    const float* phis   = (const float*)d_in[4];
    float* out = (float*)d_out;

    const int batch = in_sizes[0] / (2 * NN);   // 64
    qubit_layer_kernel<<<batch, BLK, 0, stream>>>(x, alphas, betas, thetas, phis, out);
}

// Round 13
// 9.935 us; speedup vs baseline: 1.2233x; 1.2233x over previous
//
#include <hip/hip_runtime.h>
#include <math.h>

#define NN 4096
#define BLK 512
#define EPT 8
#define PADSZ (NN + (NN >> 3))

__device__ __forceinline__ void cmul(float& ar, float& ai, float br, float bi) {
    float nr = ar * br - ai * bi;
    float ni = ar * bi + ai * br;
    ar = nr; ai = ni;
}

// new_u = u + i*w ; new_w = w + i*u  (1/sqrt2 folded into theta/phi tables, 1/8 per B6)
__device__ __forceinline__ void bfly_pair(float* vr, float* vi, int a, int b) {
    float ur = vr[a], ui = vi[a], wr = vr[b], wi = vi[b];
    vr[a] = ur - wi; vi[a] = ui + wr;
    vr[b] = wr - ui; vi[b] = wi + ur;
}
__device__ __forceinline__ void bfly3(float* vr, float* vi) {
    bfly_pair(vr, vi, 0, 1); bfly_pair(vr, vi, 2, 3); bfly_pair(vr, vi, 4, 5); bfly_pair(vr, vi, 6, 7);
    bfly_pair(vr, vi, 0, 2); bfly_pair(vr, vi, 1, 3); bfly_pair(vr, vi, 4, 6); bfly_pair(vr, vi, 5, 7);
    bfly_pair(vr, vi, 0, 4); bfly_pair(vr, vi, 1, 5); bfly_pair(vr, vi, 2, 6); bfly_pair(vr, vi, 3, 7);
}

__device__ __forceinline__ int pidx(int j) { return j + (j >> 3); }

__global__ __launch_bounds__(BLK) void qsplit_kernel(
    const float* __restrict__ x,
    const float* __restrict__ alphas, const float* __restrict__ betas,
    const float* __restrict__ thetas, const float* __restrict__ phis,
    float* __restrict__ out, int batch)
{
    __shared__ __align__(16) float2 B1[PADSZ];          // 36.9 KB exchange
    __shared__ __align__(16) float2 Zbuf[16 * 66];      // 8.4 KB  Z[lam][h], stride 66
    __shared__ __align__(16) float  ZoutR[64 * 24];     // 6 KB    out-transpose re
    __shared__ __align__(16) float  ZoutI[64 * 24];     // 6 KB
    __shared__ float2 tbl[6][64];                       // 0=in_lo 1=in_hi 2=th_lo 3=th_hi 4=ph_lo 5=ph_hi (1/8 on sets>=1)

    const int t   = threadIdx.x;
    const int bid = blockIdx.x;
    // XCD-grouped mapping: the 4 blocks of one row share bid%8 (same XCD -> x row read once)
    int b, c;
    if (batch == 64) {
        c = bid >> 6;
        b = ((bid & 7) << 3) | ((bid >> 3) & 7);
    } else {
        b = bid >> 2;
        c = bid & 3;
    }
    const int c1 = (c >> 1) & 1;
    const int c0 = c & 1;

    // ---- issue global loads first (j = 8t + k; h = t>>3, l = (t&7)*8 + k) ----
    const float* xr = x + (size_t)b * 2 * NN;
    const float* xi = xr + NN;
    float4 a0 = ((const float4*)(xr + t * EPT))[0];
    float4 a1 = ((const float4*)(xr + t * EPT))[1];
    float4 d0 = ((const float4*)(xi + t * EPT))[0];
    float4 d1 = ((const float4*)(xi + t * EPT))[1];

    // ---- build phase tables; 1/8 folded into theta AND phi halves (lo+hi chains each) ----
    if (t < 384) {
        int part = t >> 6, idx = t & 63, set = part >> 1, half = part & 1;
        float a = 0.f;
        #pragma unroll
        for (int m = 0; m < 6; ++m) {
            int q = half ? m : (6 + m);
            int bit = (idx >> (5 - m)) & 1;
            float av, bv;
            if (set == 0)      { av = alphas[q]; bv = betas[q]; }
            else if (set == 1) { av = thetas[q]; bv = 0.f; }
            else               { av = phis[q];   bv = 0.f; }
            a += bit ? bv : av;
        }
        float s, cc;
        __sincosf(a, &s, &cc);
        float sc = (set >= 1) ? 0.125f : 1.0f;
        tbl[part][idx] = make_float2(cc * sc, s * sc);
    }

    float vr[EPT], vi[EPT];
    vr[0]=a0.x; vr[1]=a0.y; vr[2]=a0.z; vr[3]=a0.w; vr[4]=a1.x; vr[5]=a1.y; vr[6]=a1.z; vr[7]=a1.w;
    vi[0]=d0.x; vi[1]=d0.y; vi[2]=d0.z; vi[3]=d0.w; vi[4]=d1.x; vi[5]=d1.y; vi[6]=d1.z; vi[7]=d1.w;

    const int s = t & 7;
    const int h = t >> 3;

    __syncthreads();   // tables ready

    // ================= PHASE A: lo-chain on this thread's h-row =================
    // D_in_lo: l = s*8 + k
    {
        const float4* elv = (const float4*)&tbl[0][s << 3];
        #pragma unroll
        for (int k = 0; k < 4; ++k) {
            float4 e2 = elv[k];
            cmul(vr[2*k],   vi[2*k],   e2.x, e2.y);
            cmul(vr[2*k+1], vi[2*k+1], e2.z, e2.w);
        }
    }
    // B6#1: bits 0-2 (regs) | exchange | bits 3-5 (regs)
    bfly3(vr, vi);
    {
        #pragma unroll
        for (int r = 0; r < EPT; ++r) B1[pidx(8 * t + r)] = make_float2(vr[r], vi[r]);
        asm volatile("" ::: "memory");
        #pragma unroll
        for (int r = 0; r < EPT; ++r) {
            float2 v = B1[pidx(((t >> 3) << 6) | (r << 3) | s)];
            vr[r] = v.x; vi[r] = v.y;
        }
    }
    bfly3(vr, vi);   // regs r = l bits 5:3
    // D_theta_lo: l = r*8 + s
    #pragma unroll
    for (int r = 0; r < EPT; ++r) {
        float2 e = tbl[2][(r << 3) | s];
        cmul(vr[r], vi[r], e.x, e.y);
    }
    // B6#2 pruned: one-sided on l bit5 (reg bit2, keep c1), bit4 (reg bit1, keep c0),
    // free on bit3 (reg pair), free on bits 2:0 (shfl over s)
    float zr[2], zi[2];
    {
        float xr4[4], xi4[4];
        #pragma unroll
        for (int q = 0; q < 4; ++q) {
            float ar = vr[q], ai = vi[q], br = vr[q + 4], bi = vi[q + 4];
            xr4[q] = c1 ? (br - ai) : (ar - bi);
            xi4[q] = c1 ? (bi + ar) : (ai + br);
        }
        float yr[2], yi[2];
        #pragma unroll
        for (int m = 0; m < 2; ++m) {
            float ar = xr4[m], ai = xi4[m], br = xr4[m + 2], bi = xi4[m + 2];
            yr[m] = c0 ? (br - ai) : (ar - bi);
            yi[m] = c0 ? (bi + ar) : (ai + br);
        }
        zr[0] = yr[0] - yi[1]; zi[0] = yi[0] + yr[1];
        zr[1] = yr[1] - yi[0]; zi[1] = yi[1] + yr[0];
        #pragma unroll
        for (int ms = 1; ms <= 4; ms <<= 1) {
            float pr0 = __shfl_xor(zr[0], ms), pi0 = __shfl_xor(zi[0], ms);
            float pr1 = __shfl_xor(zr[1], ms), pi1 = __shfl_xor(zi[1], ms);
            zr[0] -= pi0; zi[0] += pr0;
            zr[1] -= pi1; zi[1] += pr1;
        }
    }
    // D_phi_lo + Z write: l' = 16c + 8m + s ; Zbuf[lam*66 + h], lam = 8m + s
    #pragma unroll
    for (int m = 0; m < 2; ++m) {
        float2 e = tbl[4][(c << 4) | (m << 3) | s];
        cmul(zr[m], zi[m], e.x, e.y);
        Zbuf[((m << 3) | s) * 66 + h] = make_float2(zr[m], zi[m]);
    }
    __syncthreads();

    // ================= PHASE B: hi-chain on 16 owned columns (2 waves) =================
    if (t < 128) {
        const int u = t, lam = u >> 3, s2 = u & 7;
        float wr[EPT], wi[EPT];
        const float4* zp = (const float4*)&Zbuf[lam * 66 + (s2 << 3)];
        #pragma unroll
        for (int k = 0; k < 4; ++k) {
            float4 v = zp[k];
            wr[2*k] = v.x; wi[2*k] = v.y; wr[2*k+1] = v.z; wi[2*k+1] = v.w;
        }
        // D_in_hi: h = s2*8 + k
        {
            const float4* elv = (const float4*)&tbl[1][s2 << 3];
            #pragma unroll
            for (int k = 0; k < 4; ++k) {
                float4 e2 = elv[k];
                cmul(wr[2*k],   wi[2*k],   e2.x, e2.y);
                cmul(wr[2*k+1], wi[2*k+1], e2.z, e2.w);
            }
        }
        // B6hi#1
        bfly3(wr, wi);
        #pragma unroll
        for (int r = 0; r < EPT; ++r) B1[pidx(8 * u + r)] = make_float2(wr[r], wi[r]);
        asm volatile("" ::: "memory");
        #pragma unroll
        for (int r = 0; r < EPT; ++r) {
            float2 v = B1[pidx(((u >> 3) << 6) | (r << 3) | s2)];
            wr[r] = v.x; wi[r] = v.y;
        }
        bfly3(wr, wi);   // regs = h bits 5:3
        // D_theta_hi
        #pragma unroll
        for (int r = 0; r < EPT; ++r) {
            float2 e = tbl[3][(r << 3) | s2];
            cmul(wr[r], wi[r], e.x, e.y);
        }
        // B6hi#2
        bfly3(wr, wi);
        #pragma unroll
        for (int r = 0; r < EPT; ++r) B1[pidx(((u >> 3) << 6) | (r << 3) | s2)] = make_float2(wr[r], wi[r]);
        asm volatile("" ::: "memory");
        #pragma unroll
        for (int r = 0; r < EPT; ++r) {
            float2 v = B1[pidx(8 * u + r)];
            wr[r] = v.x; wi[r] = v.y;
        }
        bfly3(wr, wi);   // regs = h bits 2:0
        // D_phi_hi + Zout transpose write: h = s2*8 + k
        {
            const float4* elv = (const float4*)&tbl[5][s2 << 3];
            #pragma unroll
            for (int k = 0; k < 4; ++k) {
                float4 e2 = elv[k];
                cmul(wr[2*k],   wi[2*k],   e2.x, e2.y);
                cmul(wr[2*k+1], wi[2*k+1], e2.z, e2.w);
            }
            #pragma unroll
            for (int k = 0; k < EPT; ++k) {
                int hh = (s2 << 3) | k;
                ZoutR[hh * 24 + lam] = wr[k];
                ZoutI[hh * 24 + lam] = wi[k];
            }
        }
    }
    __syncthreads();

    // ---- coalesced stores: thread -> (plane, h, 4-float chunk) ----
    {
        const int p  = t >> 8;
        const int id = t & 255;
        const int h2 = id >> 2;
        const int q  = id & 3;
        const float* zsrc = p ? ZoutI : ZoutR;
        float4 val = *(const float4*)&zsrc[h2 * 24 + q * 4];
        *(float4*)(out + (size_t)b * 2 * NN + (size_t)p * NN + h2 * 64 + c * 16 + q * 4) = val;
    }
}

extern "C" void kernel_launch(void* const* d_in, const int* in_sizes, int n_in,
                              void* d_out, int out_size, void* d_ws, size_t ws_size,
                              hipStream_t stream) {
    const float* x      = (const float*)d_in[0];
    const float* alphas = (const float*)d_in[1];
    const float* betas  = (const float*)d_in[2];
    const float* thetas = (const float*)d_in[3];
    const float* phis   = (const float*)d_in[4];
    float* out = (float*)d_out;

    const int batch = in_sizes[0] / (2 * NN);   // 64
    qsplit_kernel<<<batch * 4, BLK, 0, stream>>>(x, alphas, betas, thetas, phis, out, batch);
}